// Round 15
// baseline (359.651 us; speedup 1.0000x reference)
//
#include <hip/hip_runtime.h>

// Soft-DTW, gamma=1.0, B=64, N=M=1024, barrier-free, linear-weight cells
// with INTEGER-EXPONENT scale tracking (no transcendentals on the chain).
//   W_true[i][j] = 2^(-v2[i][j]) (v2 = cost * log2e),
//   W[i][j] = f * (W[i-1][j] + W[i-1][j-1] + W[i][j-1]),  f = 2^(-d*log2e)
// Per-thread state is W_stored with invariant W_true = W_stored * 2^S
// (S integer). Renorm per quad: e = frexp_exp(W33); W *= 2^-e (v_ldexp);
// S += e. Neighbor import: ldexp(W_recv, S_recv - S). All scale ops are
// single-slot VALU. Transcendentals: 16 off-chain f-exp2 per quad (from the
// load ring) + ONE log2 at final output. R12/R14's chained log2/exp2 renorm
// (~200 cyc/iter on the dependency chain) is gone.
//
// Skeleton = proven R14: thread t owns cols 4t..4t+3, quad p (rows 4p..4p+3)
// at iteration j = p + t, ITER = 512. Handoff t-1 -> t: 5x __shfl_up
// (4 W + S), pipelined to iteration end. Wave boundaries (3): LDS mailbox,
// groups of 4 quads, seq counter + lgkm fence. Anchor: at p==0, S := S_recv.
// D: asm global_load_dwordx4 ring (16 outstanding), counted vmcnt(12).

#define BIGV 1.0e10f
#define LOG2E 1.4426950408889634f
#define LN2  0.6931471805599453f

constexpr int N = 1024;
constexpr int TPB = 256;
constexpr int KC = 4;                // columns per thread
constexpr int RQ = 4;                // rows per iteration (quad)
constexpr int NQ = N / RQ;           // 256 quads
constexpr int NG = NQ / 4;           // 64 groups of 4 quads
constexpr int ITER = 512;            // last real iteration: 255 + 255 = 510

__device__ __forceinline__ float fexp2(float x){float r;asm("v_exp_f32 %0, %1":"=v"(r):"v"(x));return r;}
__device__ __forceinline__ float flog2(float x){float r;asm("v_log_f32 %0, %1":"=v"(r):"v"(x));return r;}
__device__ __forceinline__ int   ffrexpe(float x){int r;asm("v_frexp_exp_i32_f32 %0, %1":"=v"(r):"v"(x));return r;}
__device__ __forceinline__ float fldexp(float x, int e){float r;asm("v_ldexp_f32 %0, %1, %2":"=v"(r):"v"(x),"v"(e));return r;}
__device__ __forceinline__ void gload4(float4& d, const float* p){
    asm volatile("global_load_dwordx4 %0, %1, off" : "=v"(d) : "v"(p));
}

__global__ __launch_bounds__(TPB, 1)
void softdtw_kernel(const float* __restrict__ D, float* __restrict__ out){
    const int b = blockIdx.x;
    const int t = threadIdx.x;
    const int lane = t & 63;
    const int w = t >> 6;
    const float* __restrict__ bp = D + (size_t)b * N * N + t * KC;

    __shared__ float pay[3][NG][4][5];   // [bnd][group][quad][4W + S-bits]
    __shared__ int seqv[3];
    if (t < 3) seqv[t] = -1;
    __syncthreads();   // once, before the pipeline

    const bool isProd = (lane == 63) && (w < 3);
    const bool isCons = (lane == 0) && (w > 0);

    float pW[KC] = {0.0f, 0.0f, 0.0f, 0.0f};   // row-above weights (my scale)
    int   S = 0;                                // scale: W_true = W * 2^S
    float luW = (t == 0) ? 1.0f : 0.0f;         // diagonal (DP[0][0]=1 for t0)
    float exW[RQ] = {0.0f, 0.0f, 0.0f, 0.0f};   // exported right-edge W
    int   exS = 0;
    float nW[RQ]  = {0.0f, 0.0f, 0.0f, 0.0f};   // shfl'd neighbor edges
    int   nS = 0;
    float mbW[4][4]; int mbS[4];
#pragma unroll
    for (int q = 0; q < 4; ++q) {
        mbS[q] = 0;
#pragma unroll
        for (int r = 0; r < 4; ++r) mbW[q][r] = 0.0f;
    }

    float4 ld[4][4];                   // [slot][row]
#pragma unroll
    for (int x = 0; x < 4; ++x) {      // prologue loads for j=0..3
        int pc = min(max(x - t, 0), NQ - 1);
        const float* a = bp + (size_t)(pc * RQ) * N;
#pragma unroll
        for (int r = 0; r < RQ; ++r) gload4(ld[x][r], a + (size_t)r * N);
    }

    for (int jb = 0; jb < ITER; jb += 4) {
#pragma unroll
        for (int u = 0; u < 4; ++u) {
            const int p = jb + u - t;
            const bool active = (unsigned)p < (unsigned)NQ;

            // mailbox group read (consumers; p%4==0 exactly at u==0)
            if (u == 0 && isCons && active) {
                const int gq = p >> 2;
                volatile int* sp = &seqv[w - 1];
                int sv; do { sv = *sp; } while (sv < gq);
                asm volatile("s_waitcnt lgkmcnt(0)" ::: "memory");
                const float* pp = &pay[w - 1][gq][0][0];
#pragma unroll
                for (int q = 0; q < 4; ++q) {
                    mbW[q][0] = pp[5*q];   mbW[q][1] = pp[5*q+1];
                    mbW[q][2] = pp[5*q+2]; mbW[q][3] = pp[5*q+3];
                    mbS[q] = __float_as_int(pp[5*q+4]);
                }
            }

            // incoming left edges (neighbor scale)
            float i0 = nW[0], i1 = nW[1], i2 = nW[2], i3 = nW[3];
            int   iS = nS;
            if (isCons) { i0 = mbW[u][0]; i1 = mbW[u][1]; i2 = mbW[u][2]; i3 = mbW[u][3]; iS = mbS[u]; }
            if (t == 0) { i0 = 0.0f; i1 = 0.0f; i2 = 0.0f; i3 = 0.0f; iS = S; }

            // anchor my scale at my first quad
            if (p == 0) S = (t == 0) ? 0 : iS;

            // oldest load batch (slot u) has landed: 16 outstanding -> 12
            asm volatile("s_waitcnt vmcnt(12)" ::: "memory");
            __builtin_amdgcn_sched_barrier(0);

            // off-chain per-cell factors f = 2^(-d*log2e)
            float f[16];
#pragma unroll
            for (int r = 0; r < RQ; ++r) {
                const float4 dv = ld[u][r];
                f[r*4+0] = fexp2(-LOG2E * dv.x);
                f[r*4+1] = fexp2(-LOG2E * dv.y);
                f[r*4+2] = fexp2(-LOG2E * dv.z);
                f[r*4+3] = fexp2(-LOG2E * dv.w);
            }

            // import edges into my scale (pure VALU)
            const int dS = iS - S;
            float eW[4];
            eW[0] = fldexp(i0, dS); eW[1] = fldexp(i1, dS);
            eW[2] = fldexp(i2, dS); eW[3] = fldexp(i3, dS);

            // ---- 16 cells: W = f*(up + diag + left) ----
            float a0 = pW[0], a1 = pW[1], a2 = pW[2], a3 = pW[3];
            float dg = luW;
            float eR[4];
#pragma unroll
            for (int r = 0; r < RQ; ++r) {
                float t0 = dg + eW[r];
                float s01 = a0 + a1, s12 = a1 + a2, s23 = a2 + a3; // off-chain
                float W0 = f[r*4+0] * (a0 + t0);
                float W1 = f[r*4+1] * (s01 + W0);
                float W2 = f[r*4+2] * (s12 + W1);
                float W3 = f[r*4+3] * (s23 + W2);
                eR[r] = W3;
                dg = eW[r];
                a0 = W0; a1 = W1; a2 = W2; a3 = W3;
            }

            // renorm by W33's exponent (integer scale, no transcendentals)
            const int e = ffrexpe(a3);
            const float sc = fldexp(1.0f, -e);

            if (active) {                  // masked commit
                pW[0] = a0 * sc; pW[1] = a1 * sc; pW[2] = a2 * sc; pW[3] = a3 * sc;
                luW = dg * sc;
                exW[0] = eR[0] * sc; exW[1] = eR[1] * sc;
                exW[2] = eR[2] * sc; exW[3] = eR[3] * sc;
                S += e; exS = S;
            }

            // producer: payload each quad; seq bump at group end (u==2)
            if (isProd && active) {
                volatile float* pp = &pay[w][p >> 2][p & 3][0];
                pp[0] = exW[0]; pp[1] = exW[1]; pp[2] = exW[2]; pp[3] = exW[3];
                pp[4] = __int_as_float(exS);
            }
            if (u == 2 && isProd && active) {
                asm volatile("s_waitcnt lgkmcnt(0)" ::: "memory");
                *(volatile int*)&seqv[w] = (p >> 2);
            }

            // issue D loads for iteration j+4 into slot u
            {
                int pc = min(max(p + 4, 0), NQ - 1);
                const float* a = bp + (size_t)(pc * RQ) * N;
#pragma unroll
                for (int r = 0; r < RQ; ++r) gload4(ld[u][r], a + (size_t)r * N);
            }

            // pipelined handoff for NEXT iteration
            nW[0] = __shfl_up(exW[0], 1);
            nW[1] = __shfl_up(exW[1], 1);
            nW[2] = __shfl_up(exW[2], 1);
            nW[3] = __shfl_up(exW[3], 1);
            nS    = __shfl_up(exS, 1);
        }
    }

    // v2 = -(log2(W33) + S); cost = v2 * ln2.  (thread 255's last quad)
    if (t == TPB - 1) out[b] = -(flog2(pW[KC - 1]) + (float)S) * LN2;
}

extern "C" void kernel_launch(void* const* d_in, const int* in_sizes, int n_in,
                              void* d_out, int out_size, void* d_ws, size_t ws_size,
                              hipStream_t stream) {
    const float* D = (const float*)d_in[0];
    float* out = (float*)d_out;
    const int B = in_sizes[0] / (N * N);
    softdtw_kernel<<<B, TPB, 0, stream>>>(D, out);
}

// Round 16
// 263.683 us; speedup vs baseline: 1.3640x; 1.3640x over previous
//
#include <hip/hip_runtime.h>

// Soft-DTW, gamma=1.0, B=64, N=M=1024, barrier-free, linear-weight cells,
// integer-exponent scale tracking (R15 numerics, proven absmax 0.0).
// R16 change: KC=8 columns/thread, TPB=128 (2 waves). Rationale: the
// cross-round invariant (~350us for R8/R11/R12/R14/R15) tracks per-CU L1
// line-requests (staircase rows -> every 16B lane-load is its own line).
// KC=8 halves line-requests/CU (128 threads x 4 rows = 512/iter) and halves
// the pipeline-fill skew (ITER = 256+127 = 384 vs 511).
//
// Cell: W = f*(up + diag + left), f = 2^(-d*log2e) (off-chain, from load
// ring). Scale invariant W_true = W * 2^S, S integer; renorm per quad via
// v_frexp_exp_i32_f32 + v_ldexp_f32 (no transcendentals on the chain).
// Handoff t-1 -> t: 5x __shfl_up (4 right-edge W + S), pipelined to iter end.
// One wave boundary: LDS mailbox, groups of 4 quads, seq + lgkm fence.
// D: asm global_load_dwordx4 ring, depth 2 (16 outstanding), vmcnt(8).

#define LOG2E 1.4426950408889634f
#define LN2  0.6931471805599453f

constexpr int N = 1024;
constexpr int TPB = 128;
constexpr int KC = 8;                // columns per thread
constexpr int RQ = 4;                // rows per iteration (quad)
constexpr int NQ = N / RQ;           // 256 quads
constexpr int NG = NQ / 4;           // 64 groups of 4 quads
constexpr int ITER = 384;            // last real iteration: 255 + 127 = 382

__device__ __forceinline__ float fexp2(float x){float r;asm("v_exp_f32 %0, %1":"=v"(r):"v"(x));return r;}
__device__ __forceinline__ float flog2(float x){float r;asm("v_log_f32 %0, %1":"=v"(r):"v"(x));return r;}
__device__ __forceinline__ int   ffrexpe(float x){int r;asm("v_frexp_exp_i32_f32 %0, %1":"=v"(r):"v"(x));return r;}
__device__ __forceinline__ float fldexp(float x, int e){float r;asm("v_ldexp_f32 %0, %1, %2":"=v"(r):"v"(x),"v"(e));return r;}
__device__ __forceinline__ void gload4(float4& d, const float* p){
    asm volatile("global_load_dwordx4 %0, %1, off" : "=v"(d) : "v"(p));
}

__global__ __launch_bounds__(TPB, 1)
void softdtw_kernel(const float* __restrict__ D, float* __restrict__ out){
    const int b = blockIdx.x;
    const int t = threadIdx.x;
    const int lane = t & 63;
    const int w = t >> 6;
    const float* __restrict__ bp = D + (size_t)b * N * N + t * KC;

    __shared__ float pay[NG][4][5];      // [group][quad][4 edge-W + S-bits]
    __shared__ int seqv;
    if (t == 0) seqv = -1;
    __syncthreads();   // once, before the pipeline

    const bool isProd = (lane == 63) && (w == 0);
    const bool isCons = (lane == 0) && (w == 1);

    float pW[KC] = {0,0,0,0,0,0,0,0};    // row-above weights (my scale)
    int   S = 0;                          // scale: W_true = W * 2^S
    float luW = (t == 0) ? 1.0f : 0.0f;   // diagonal (DP[0][0]=1 for t0)
    float exW[RQ] = {0,0,0,0};            // exported right-edge W
    int   exS = 0;
    float nW[RQ] = {0,0,0,0};             // shfl'd neighbor edges
    int   nS = 0;
    float mbW[4][4]; int mbS[4];
#pragma unroll
    for (int q = 0; q < 4; ++q) {
        mbS[q] = 0;
#pragma unroll
        for (int r = 0; r < 4; ++r) mbW[q][r] = 0.0f;
    }

    float4 ld[2][RQ][2];                 // [slot][row][half]
#pragma unroll
    for (int x = 0; x < 2; ++x) {        // prologue loads for j=0,1
        int pc = min(max(x - t, 0), NQ - 1);
        const float* a = bp + (size_t)(pc * RQ) * N;
#pragma unroll
        for (int r = 0; r < RQ; ++r) {
            gload4(ld[x][r][0], a + (size_t)r * N);
            gload4(ld[x][r][1], a + (size_t)r * N + 4);
        }
    }

    for (int jb = 0; jb < ITER; jb += 4) {
#pragma unroll
        for (int u = 0; u < 4; ++u) {
            const int p = jb + u - t;
            const bool active = (unsigned)p < (unsigned)NQ;
            const int slot = u & 1;

            // mailbox group read (consumer t=64; p%4==0 exactly at u==0)
            if (u == 0 && isCons && active) {
                const int gq = p >> 2;
                volatile int* sp = &seqv;
                int sv; do { sv = *sp; } while (sv < gq);
                asm volatile("s_waitcnt lgkmcnt(0)" ::: "memory");
                const float* pp = &pay[gq][0][0];
#pragma unroll
                for (int q = 0; q < 4; ++q) {
                    mbW[q][0] = pp[5*q];   mbW[q][1] = pp[5*q+1];
                    mbW[q][2] = pp[5*q+2]; mbW[q][3] = pp[5*q+3];
                    mbS[q] = __float_as_int(pp[5*q+4]);
                }
            }

            // incoming left edges (neighbor scale)
            float i0 = nW[0], i1 = nW[1], i2 = nW[2], i3 = nW[3];
            int   iS = nS;
            if (isCons) { i0 = mbW[u][0]; i1 = mbW[u][1]; i2 = mbW[u][2]; i3 = mbW[u][3]; iS = mbS[u]; }
            if (t == 0) { i0 = 0.0f; i1 = 0.0f; i2 = 0.0f; i3 = 0.0f; iS = S; }

            // anchor my scale at my first quad
            if (p == 0) S = (t == 0) ? 0 : iS;

            // oldest load batch (slot) landed: 16 outstanding -> 8
            asm volatile("s_waitcnt vmcnt(8)" ::: "memory");
            __builtin_amdgcn_sched_barrier(0);

            // import edges into my scale (pure VALU)
            const int dS = iS - S;
            float eW[RQ];
            eW[0] = fldexp(i0, dS); eW[1] = fldexp(i1, dS);
            eW[2] = fldexp(i2, dS); eW[3] = fldexp(i3, dS);

            // ---- 32 cells: W = f*(up + diag + left), 8-wide rows ----
            float a0 = pW[0], a1 = pW[1], a2 = pW[2], a3 = pW[3];
            float a4 = pW[4], a5 = pW[5], a6 = pW[6], a7 = pW[7];
            float dg = luW;
            float eR[RQ];
#pragma unroll
            for (int r = 0; r < RQ; ++r) {
                const float4 d0 = ld[slot][r][0];
                const float4 d1 = ld[slot][r][1];
                float f0 = fexp2(-LOG2E * d0.x), f1 = fexp2(-LOG2E * d0.y);
                float f2 = fexp2(-LOG2E * d0.z), f3 = fexp2(-LOG2E * d0.w);
                float f4 = fexp2(-LOG2E * d1.x), f5 = fexp2(-LOG2E * d1.y);
                float f6 = fexp2(-LOG2E * d1.z), f7 = fexp2(-LOG2E * d1.w);
                // off-chain neighbor sums
                float s01 = a0 + a1, s12 = a1 + a2, s23 = a2 + a3, s34 = a3 + a4;
                float s45 = a4 + a5, s56 = a5 + a6, s67 = a6 + a7;
                float t0 = dg + eW[r];
                float W0 = f0 * (a0 + t0);
                float W1 = f1 * (s01 + W0);
                float W2 = f2 * (s12 + W1);
                float W3 = f3 * (s23 + W2);
                float W4 = f4 * (s34 + W3);
                float W5 = f5 * (s45 + W4);
                float W6 = f6 * (s56 + W5);
                float W7 = f7 * (s67 + W6);
                eR[r] = W7;
                dg = eW[r];
                a0 = W0; a1 = W1; a2 = W2; a3 = W3;
                a4 = W4; a5 = W5; a6 = W6; a7 = W7;
            }

            // renorm by W77's exponent (integer scale)
            const int e = ffrexpe(a7);
            const float sc = fldexp(1.0f, -e);

            if (active) {                  // masked commit
                pW[0] = a0 * sc; pW[1] = a1 * sc; pW[2] = a2 * sc; pW[3] = a3 * sc;
                pW[4] = a4 * sc; pW[5] = a5 * sc; pW[6] = a6 * sc; pW[7] = a7 * sc;
                luW = dg * sc;
                exW[0] = eR[0] * sc; exW[1] = eR[1] * sc;
                exW[2] = eR[2] * sc; exW[3] = eR[3] * sc;
                S += e; exS = S;
            }

            // producer: payload each quad; seq bump at group end (u==2)
            if (isProd && active) {
                volatile float* pp = &pay[p >> 2][p & 3][0];
                pp[0] = exW[0]; pp[1] = exW[1]; pp[2] = exW[2]; pp[3] = exW[3];
                pp[4] = __int_as_float(exS);
            }
            if (u == 2 && isProd && active) {
                asm volatile("s_waitcnt lgkmcnt(0)" ::: "memory");
                *(volatile int*)&seqv = (p >> 2);
            }

            // issue D loads for iteration j+2 into the just-consumed slot
            {
                int pc = min(max(p + 2, 0), NQ - 1);
                const float* a = bp + (size_t)(pc * RQ) * N;
#pragma unroll
                for (int r = 0; r < RQ; ++r) {
                    gload4(ld[slot][r][0], a + (size_t)r * N);
                    gload4(ld[slot][r][1], a + (size_t)r * N + 4);
                }
            }

            // pipelined handoff for NEXT iteration
            nW[0] = __shfl_up(exW[0], 1);
            nW[1] = __shfl_up(exW[1], 1);
            nW[2] = __shfl_up(exW[2], 1);
            nW[3] = __shfl_up(exW[3], 1);
            nS    = __shfl_up(exS, 1);
        }
    }

    // v2 = -(log2(W) + S); cost = v2 * ln2.  (thread 127's last quad)
    if (t == TPB - 1) out[b] = -(flog2(pW[KC - 1]) + (float)S) * LN2;
}

extern "C" void kernel_launch(void* const* d_in, const int* in_sizes, int n_in,
                              void* d_out, int out_size, void* d_ws, size_t ws_size,
                              hipStream_t stream) {
    const float* D = (const float*)d_in[0];
    float* out = (float*)d_out;
    const int B = in_sizes[0] / (N * N);
    softdtw_kernel<<<B, TPB, 0, stream>>>(D, out);
}